// Round 1
// baseline (3450.376 us; speedup 1.0000x reference)
//
#include <hip/hip_runtime.h>
#include <cstdint>
#include <cstddef>

// ---------------------------------------------------------------------------
// RWKV-style TimeMix: 5 bf16 MFMA GEMMs + chunk-parallel linear scan.
//   r  = sigmoid(x @ Wr^T); ewk = exp(x@Wk^T - exp(x@Ww^T)); v = x @ Wv^T
//   scan over s:  num = dec*num + ewk*v ; den = dec*den + ewk ; y = r*num/(den+1e-8)
//   out = y @ Wo^T ; final_state = (num,den) after S steps
// GEMM kernel = m97 ladder structure: 128x128 tile, BK=32, 4 waves 2x2,
// 4x4 mfma_f32_16x16x32_bf16 per wave, global_load_lds width=16 staging.
// ---------------------------------------------------------------------------

typedef unsigned short u16;
typedef __attribute__((ext_vector_type(8))) __bf16 bf16x8;
typedef __attribute__((ext_vector_type(4))) float f32x4;

#define AS1 __attribute__((address_space(1)))
#define AS3 __attribute__((address_space(3)))

static constexpr int BATCH  = 4;
static constexpr int SEQ    = 4096;
static constexpr int DIM    = 2048;
static constexpr int MROWS  = BATCH * SEQ;     // 16384
static constexpr int NCHUNK = 128;             // scan chunks per sequence
static constexpr int CLEN   = SEQ / NCHUNK;    // 32

__device__ __forceinline__ u16 f2bf(float f) {
    uint32_t u = __float_as_uint(f);
    u += 0x7fffu + ((u >> 16) & 1u);           // round-to-nearest-even
    return (u16)(u >> 16);
}
__device__ __forceinline__ float bfl(uint32_t w) { return __uint_as_float(w << 16); }
__device__ __forceinline__ float bfh(uint32_t w) { return __uint_as_float(w & 0xffff0000u); }
__device__ __forceinline__ void unpack8(uint4 u, float* f) {
    f[0] = bfl(u.x); f[1] = bfh(u.x); f[2] = bfl(u.y); f[3] = bfh(u.y);
    f[4] = bfl(u.z); f[5] = bfh(u.z); f[6] = bfl(u.w); f[7] = bfh(u.w);
}
__device__ __forceinline__ uint32_t pack2(float a, float b) {
    return (uint32_t)f2bf(a) | ((uint32_t)f2bf(b) << 16);
}

// fp32 -> bf16 conversion, 4 elems/thread
__global__ void cvt_kernel(const float* __restrict__ in, u16* __restrict__ out) {
    size_t i = ((size_t)blockIdx.x * blockDim.x + threadIdx.x) * 4;
    float4 f = *(const float4*)(in + i);
    u16 o0 = f2bf(f.x), o1 = f2bf(f.y), o2 = f2bf(f.z), o3 = f2bf(f.w);
    uint2 p = { (uint32_t)o0 | ((uint32_t)o1 << 16), (uint32_t)o2 | ((uint32_t)o3 << 16) };
    *(uint2*)(out + i) = p;
}

// C[m,n] = sum_k A[m,k]*W[n,k]; EPI: 0 = fp32 store, 1 = sigmoid->bf16, 2 = bf16
template<int EPI>
__global__ void gemm_nt(const u16* __restrict__ A, const u16* __restrict__ Bw,
                        float* __restrict__ Cf, u16* __restrict__ Cb) {
    __shared__ __align__(16) u16 As[128 * 32];
    __shared__ __align__(16) u16 Bs[128 * 32];
    const int tid  = threadIdx.x;
    const int lane = tid & 63;
    const int wv   = tid >> 6;
    const int wr   = (wv >> 1) * 64;       // wave row offset in tile
    const int wc   = (wv & 1) * 64;        // wave col offset in tile
    const int m0   = blockIdx.x * 128;
    const int n0   = blockIdx.y * 128;
    const int fr   = lane & 15;
    const int kg   = (lane >> 4) * 8;      // k-group element offset
    const int srow = tid >> 2;             // staging row 0..63
    const int skc  = (tid & 3) * 8;        // staging k element offset

    f32x4 acc[4][4] = {};
    const size_t a_base = (size_t)(m0 + srow) * DIM + skc;
    const size_t b_base = (size_t)(n0 + srow) * DIM + skc;

    for (int k0 = 0; k0 < DIM; k0 += 32) {
        __builtin_amdgcn_global_load_lds((AS1 void*)(A + a_base + k0),
                                         (AS3 void*)(As + tid * 8), 16, 0, 0);
        __builtin_amdgcn_global_load_lds((AS1 void*)(A + a_base + (size_t)64 * DIM + k0),
                                         (AS3 void*)(As + (tid + 256) * 8), 16, 0, 0);
        __builtin_amdgcn_global_load_lds((AS1 void*)(Bw + b_base + k0),
                                         (AS3 void*)(Bs + tid * 8), 16, 0, 0);
        __builtin_amdgcn_global_load_lds((AS1 void*)(Bw + b_base + (size_t)64 * DIM + k0),
                                         (AS3 void*)(Bs + (tid + 256) * 8), 16, 0, 0);
        __syncthreads();
        bf16x8 af[4], bfr[4];
#pragma unroll
        for (int i = 0; i < 4; ++i)
            af[i] = *(const bf16x8*)(As + (wr + i * 16 + fr) * 32 + kg);
#pragma unroll
        for (int j = 0; j < 4; ++j)
            bfr[j] = *(const bf16x8*)(Bs + (wc + j * 16 + fr) * 32 + kg);
#pragma unroll
        for (int i = 0; i < 4; ++i)
#pragma unroll
            for (int j = 0; j < 4; ++j)
                acc[i][j] = __builtin_amdgcn_mfma_f32_16x16x32_bf16(af[i], bfr[j], acc[i][j], 0, 0, 0);
        __syncthreads();
    }

    const int rb_ = (lane >> 4) * 4;
#pragma unroll
    for (int i = 0; i < 4; ++i) {
#pragma unroll
        for (int j = 0; j < 4; ++j) {
#pragma unroll
            for (int rg = 0; rg < 4; ++rg) {
                const int row = m0 + wr + i * 16 + rb_ + rg;
                const int col = n0 + wc + j * 16 + fr;
                const float val = acc[i][j][rg];
                if (EPI == 0) {
                    Cf[(size_t)row * DIM + col] = val;
                } else if (EPI == 1) {
                    Cb[(size_t)row * DIM + col] = f2bf(1.0f / (1.0f + expf(-val)));
                } else {
                    Cb[(size_t)row * DIM + col] = f2bf(val);
                }
            }
        }
    }
}

// dual-accumulator GEMM: ewk = exp( x@Wk^T - exp(x@Ww^T) ), bf16 out
__global__ void gemm_ewk(const u16* __restrict__ A, const u16* __restrict__ Wk,
                         const u16* __restrict__ Ww, u16* __restrict__ E) {
    __shared__ __align__(16) u16 As[128 * 32];
    __shared__ __align__(16) u16 Ks[128 * 32];
    __shared__ __align__(16) u16 Ws[128 * 32];
    const int tid  = threadIdx.x;
    const int lane = tid & 63;
    const int wv   = tid >> 6;
    const int wr   = (wv >> 1) * 64;
    const int wc   = (wv & 1) * 64;
    const int m0   = blockIdx.x * 128;
    const int n0   = blockIdx.y * 128;
    const int fr   = lane & 15;
    const int kg   = (lane >> 4) * 8;
    const int srow = tid >> 2;
    const int skc  = (tid & 3) * 8;

    f32x4 acck[4][4] = {};
    f32x4 accw[4][4] = {};
    const size_t a_base = (size_t)(m0 + srow) * DIM + skc;
    const size_t b_base = (size_t)(n0 + srow) * DIM + skc;

    for (int k0 = 0; k0 < DIM; k0 += 32) {
        __builtin_amdgcn_global_load_lds((AS1 void*)(A + a_base + k0),
                                         (AS3 void*)(As + tid * 8), 16, 0, 0);
        __builtin_amdgcn_global_load_lds((AS1 void*)(A + a_base + (size_t)64 * DIM + k0),
                                         (AS3 void*)(As + (tid + 256) * 8), 16, 0, 0);
        __builtin_amdgcn_global_load_lds((AS1 void*)(Wk + b_base + k0),
                                         (AS3 void*)(Ks + tid * 8), 16, 0, 0);
        __builtin_amdgcn_global_load_lds((AS1 void*)(Wk + b_base + (size_t)64 * DIM + k0),
                                         (AS3 void*)(Ks + (tid + 256) * 8), 16, 0, 0);
        __builtin_amdgcn_global_load_lds((AS1 void*)(Ww + b_base + k0),
                                         (AS3 void*)(Ws + tid * 8), 16, 0, 0);
        __builtin_amdgcn_global_load_lds((AS1 void*)(Ww + b_base + (size_t)64 * DIM + k0),
                                         (AS3 void*)(Ws + (tid + 256) * 8), 16, 0, 0);
        __syncthreads();
        bf16x8 af[4], kf[4], wf[4];
#pragma unroll
        for (int i = 0; i < 4; ++i)
            af[i] = *(const bf16x8*)(As + (wr + i * 16 + fr) * 32 + kg);
#pragma unroll
        for (int j = 0; j < 4; ++j) {
            kf[j] = *(const bf16x8*)(Ks + (wc + j * 16 + fr) * 32 + kg);
            wf[j] = *(const bf16x8*)(Ws + (wc + j * 16 + fr) * 32 + kg);
        }
#pragma unroll
        for (int i = 0; i < 4; ++i)
#pragma unroll
            for (int j = 0; j < 4; ++j) {
                acck[i][j] = __builtin_amdgcn_mfma_f32_16x16x32_bf16(af[i], kf[j], acck[i][j], 0, 0, 0);
                accw[i][j] = __builtin_amdgcn_mfma_f32_16x16x32_bf16(af[i], wf[j], accw[i][j], 0, 0, 0);
            }
        __syncthreads();
    }

    const int rb_ = (lane >> 4) * 4;
#pragma unroll
    for (int i = 0; i < 4; ++i)
#pragma unroll
        for (int j = 0; j < 4; ++j)
#pragma unroll
            for (int rg = 0; rg < 4; ++rg) {
                const int row = m0 + wr + i * 16 + rb_ + rg;
                const int col = n0 + wc + j * 16 + fr;
                const float e = expf(acck[i][j][rg] - expf(accw[i][j][rg]));
                E[(size_t)row * DIM + col] = f2bf(e);
            }
}

// pass 1: per-chunk carries with zero init. grid = BATCH*NCHUNK blocks, 256 thr, 8 ch/thread
__global__ void scan_carry(const u16* __restrict__ ewk, const u16* __restrict__ v,
                           const float* __restrict__ td,
                           float* __restrict__ carN, float* __restrict__ carD) {
    const int b  = blockIdx.x / NCHUNK;
    const int c  = blockIdx.x % NCHUNK;
    const int d0 = threadIdx.x * 8;
    float dec[8], num[8], den[8];
#pragma unroll
    for (int z = 0; z < 8; ++z) { dec[z] = expf(td[d0 + z]); num[z] = 0.f; den[z] = 0.f; }
    const size_t base = ((size_t)b * SEQ + (size_t)c * CLEN) * DIM + d0;
    for (int t = 0; t < CLEN; ++t) {
        uint4 eu = *(const uint4*)(ewk + base + (size_t)t * DIM);
        uint4 vu = *(const uint4*)(v   + base + (size_t)t * DIM);
        float e[8], vv[8];
        unpack8(eu, e); unpack8(vu, vv);
#pragma unroll
        for (int z = 0; z < 8; ++z) {
            num[z] = dec[z] * num[z] + e[z] * vv[z];
            den[z] = dec[z] * den[z] + e[z];
        }
    }
    const size_t cb = ((size_t)(b * NCHUNK + c)) * DIM + d0;
    *(float4*)(carN + cb)     = { num[0], num[1], num[2], num[3] };
    *(float4*)(carN + cb + 4) = { num[4], num[5], num[6], num[7] };
    *(float4*)(carD + cb)     = { den[0], den[1], den[2], den[3] };
    *(float4*)(carD + cb + 4) = { den[4], den[5], den[6], den[7] };
}

// pass 2: sequential compose over chunks; writes chunk-start states + final_state
__global__ void scan_combine(const float* __restrict__ carN, const float* __restrict__ carD,
                             const float* __restrict__ td,
                             float* __restrict__ stN, float* __restrict__ stD,
                             float* __restrict__ fs) {
    const int i = blockIdx.x * 256 + threadIdx.x;   // 0 .. BATCH*DIM-1
    const int b = i >> 11;
    const int d = i & (DIM - 1);
    const float decL = expf(td[d] * (float)CLEN);
    float num = 0.f, den = 0.f;
    for (int c = 0; c < NCHUNK; ++c) {
        const size_t idx = ((size_t)(b * NCHUNK + c)) * DIM + d;
        stN[idx] = num; stD[idx] = den;
        num = decL * num + carN[idx];
        den = decL * den + carD[idx];
    }
    fs[(size_t)b * 2 * DIM + d]       = num;
    fs[(size_t)b * 2 * DIM + DIM + d] = den;
}

// pass 3: re-scan from true start state, emit y = r * num/(den+1e-8) as bf16
__global__ void scan_apply(const u16* __restrict__ ewk, const u16* __restrict__ v,
                           const u16* __restrict__ r, const float* __restrict__ td,
                           const float* __restrict__ stN, const float* __restrict__ stD,
                           u16* __restrict__ y) {
    const int b  = blockIdx.x / NCHUNK;
    const int c  = blockIdx.x % NCHUNK;
    const int d0 = threadIdx.x * 8;
    float dec[8], num[8], den[8];
    const size_t sb = ((size_t)(b * NCHUNK + c)) * DIM + d0;
    {
        float4 n0_ = *(const float4*)(stN + sb), n1_ = *(const float4*)(stN + sb + 4);
        float4 e0_ = *(const float4*)(stD + sb), e1_ = *(const float4*)(stD + sb + 4);
        num[0]=n0_.x; num[1]=n0_.y; num[2]=n0_.z; num[3]=n0_.w;
        num[4]=n1_.x; num[5]=n1_.y; num[6]=n1_.z; num[7]=n1_.w;
        den[0]=e0_.x; den[1]=e0_.y; den[2]=e0_.z; den[3]=e0_.w;
        den[4]=e1_.x; den[5]=e1_.y; den[6]=e1_.z; den[7]=e1_.w;
    }
#pragma unroll
    for (int z = 0; z < 8; ++z) dec[z] = expf(td[d0 + z]);
    const size_t base = ((size_t)b * SEQ + (size_t)c * CLEN) * DIM + d0;
    for (int t = 0; t < CLEN; ++t) {
        uint4 eu = *(const uint4*)(ewk + base + (size_t)t * DIM);
        uint4 vu = *(const uint4*)(v   + base + (size_t)t * DIM);
        uint4 ru = *(const uint4*)(r   + base + (size_t)t * DIM);
        float e[8], vv[8], rr[8], yy[8];
        unpack8(eu, e); unpack8(vu, vv); unpack8(ru, rr);
#pragma unroll
        for (int z = 0; z < 8; ++z) {
            num[z] = dec[z] * num[z] + e[z] * vv[z];
            den[z] = dec[z] * den[z] + e[z];
            yy[z]  = rr[z] * (num[z] / (den[z] + 1e-8f));
        }
        uint4 o = { pack2(yy[0], yy[1]), pack2(yy[2], yy[3]),
                    pack2(yy[4], yy[5]), pack2(yy[6], yy[7]) };
        *(uint4*)(y + base + (size_t)t * DIM) = o;
    }
}

extern "C" void kernel_launch(void* const* d_in, const int* in_sizes, int n_in,
                              void* d_out, int out_size, void* d_ws, size_t ws_size,
                              hipStream_t stream) {
    const float* x  = (const float*)d_in[0];
    const float* Wr = (const float*)d_in[1];
    const float* Ww = (const float*)d_in[2];
    const float* Wk = (const float*)d_in[3];
    const float* Wv = (const float*)d_in[4];
    const float* Wo = (const float*)d_in[5];
    const float* td = (const float*)d_in[6];
    float* out = (float*)d_out;
    float* fs  = out + (size_t)MROWS * DIM;   // final_state [B,2,D]

    // workspace carve-up (~376 MiB)
    uint8_t* w = (uint8_t*)d_ws;
    auto take = [&](size_t bytes) { void* p = (void*)w; w += bytes; return p; };
    u16* xb   = (u16*)take((size_t)MROWS * DIM * 2);
    u16* Wrb  = (u16*)take((size_t)DIM * DIM * 2);
    u16* Wwb  = (u16*)take((size_t)DIM * DIM * 2);
    u16* Wkb  = (u16*)take((size_t)DIM * DIM * 2);
    u16* Wvb  = (u16*)take((size_t)DIM * DIM * 2);
    u16* Wob  = (u16*)take((size_t)DIM * DIM * 2);
    u16* rb   = (u16*)take((size_t)MROWS * DIM * 2);
    u16* vb   = (u16*)take((size_t)MROWS * DIM * 2);
    u16* ewkb = (u16*)take((size_t)MROWS * DIM * 2);
    u16* yb   = (u16*)take((size_t)MROWS * DIM * 2);
    float* carN = (float*)take((size_t)BATCH * NCHUNK * DIM * 4);
    float* carD = (float*)take((size_t)BATCH * NCHUNK * DIM * 4);
    float* stN  = (float*)take((size_t)BATCH * NCHUNK * DIM * 4);
    float* stD  = (float*)take((size_t)BATCH * NCHUNK * DIM * 4);

    // bf16 conversions
    cvt_kernel<<<(MROWS * DIM) / 1024, 256, 0, stream>>>(x, xb);
    cvt_kernel<<<(DIM * DIM) / 1024, 256, 0, stream>>>(Wr, Wrb);
    cvt_kernel<<<(DIM * DIM) / 1024, 256, 0, stream>>>(Ww, Wwb);
    cvt_kernel<<<(DIM * DIM) / 1024, 256, 0, stream>>>(Wk, Wkb);
    cvt_kernel<<<(DIM * DIM) / 1024, 256, 0, stream>>>(Wv, Wvb);
    cvt_kernel<<<(DIM * DIM) / 1024, 256, 0, stream>>>(Wo, Wob);

    dim3 gg(MROWS / 128, DIM / 128);
    gemm_nt<1><<<gg, 256, 0, stream>>>(xb, Wrb, nullptr, rb);   // r = sigmoid
    gemm_nt<2><<<gg, 256, 0, stream>>>(xb, Wvb, nullptr, vb);   // v
    gemm_ewk  <<<gg, 256, 0, stream>>>(xb, Wkb, Wwb, ewkb);     // ewk

    scan_carry  <<<BATCH * NCHUNK, 256, 0, stream>>>(ewkb, vb, td, carN, carD);
    scan_combine<<<(BATCH * DIM) / 256, 256, 0, stream>>>(carN, carD, td, stN, stD, fs);
    scan_apply  <<<BATCH * NCHUNK, 256, 0, stream>>>(ewkb, vb, rb, td, stN, stD, yb);

    gemm_nt<0><<<gg, 256, 0, stream>>>(yb, Wob, out, nullptr);  // out fp32
}

// Round 2
// 1184.407 us; speedup vs baseline: 2.9132x; 2.9132x over previous
//
#include <hip/hip_runtime.h>
#include <cstdint>
#include <cstddef>

// ---------------------------------------------------------------------------
// RWKV-style TimeMix: 5 bf16 MFMA GEMMs + chunk-parallel linear scan.
//   r  = sigmoid(x @ Wr^T); ewk = exp(x@Wk^T - exp(x@Ww^T)); v = x @ Wv^T
//   scan over s:  num = dec*num + ewk*v ; den = dec*den + ewk ; y = r*num/(den+1e-8)
//   out = y @ Wo^T ; final_state = (num,den) after S steps
// GEMM kernel = m97 ladder structure: 128x128 tile, BK=32, 4 waves 2x2,
// 4x4 mfma_f32_16x16x32_bf16 per wave, global_load_lds width=16 staging.
// R2: __launch_bounds__(256,2) — without it hipcc compiles for 1024-thr
// blocks -> 128-reg/wave cap -> gemm_ewk (needs ~210) spilled accumulators
// to scratch (13 GB HBM traffic, 2.5 ms).
// ---------------------------------------------------------------------------

typedef unsigned short u16;
typedef __attribute__((ext_vector_type(8))) __bf16 bf16x8;
typedef __attribute__((ext_vector_type(4))) float f32x4;

#define AS1 __attribute__((address_space(1)))
#define AS3 __attribute__((address_space(3)))

static constexpr int BATCH  = 4;
static constexpr int SEQ    = 4096;
static constexpr int DIM    = 2048;
static constexpr int MROWS  = BATCH * SEQ;     // 16384
static constexpr int NCHUNK = 128;             // scan chunks per sequence
static constexpr int CLEN   = SEQ / NCHUNK;    // 32

__device__ __forceinline__ u16 f2bf(float f) {
    uint32_t u = __float_as_uint(f);
    u += 0x7fffu + ((u >> 16) & 1u);           // round-to-nearest-even
    return (u16)(u >> 16);
}
__device__ __forceinline__ float bfl(uint32_t w) { return __uint_as_float(w << 16); }
__device__ __forceinline__ float bfh(uint32_t w) { return __uint_as_float(w & 0xffff0000u); }
__device__ __forceinline__ void unpack8(uint4 u, float* f) {
    f[0] = bfl(u.x); f[1] = bfh(u.x); f[2] = bfl(u.y); f[3] = bfh(u.y);
    f[4] = bfl(u.z); f[5] = bfh(u.z); f[6] = bfl(u.w); f[7] = bfh(u.w);
}
__device__ __forceinline__ uint32_t pack2(float a, float b) {
    return (uint32_t)f2bf(a) | ((uint32_t)f2bf(b) << 16);
}

// fp32 -> bf16 conversion, 4 elems/thread
__global__ void __launch_bounds__(256) cvt_kernel(const float* __restrict__ in, u16* __restrict__ out) {
    size_t i = ((size_t)blockIdx.x * blockDim.x + threadIdx.x) * 4;
    float4 f = *(const float4*)(in + i);
    u16 o0 = f2bf(f.x), o1 = f2bf(f.y), o2 = f2bf(f.z), o3 = f2bf(f.w);
    uint2 p = { (uint32_t)o0 | ((uint32_t)o1 << 16), (uint32_t)o2 | ((uint32_t)o3 << 16) };
    *(uint2*)(out + i) = p;
}

// C[m,n] = sum_k A[m,k]*W[n,k]; EPI: 0 = fp32 store, 1 = sigmoid->bf16, 2 = bf16
template<int EPI>
__global__ void __launch_bounds__(256, 2)
gemm_nt(const u16* __restrict__ A, const u16* __restrict__ Bw,
        float* __restrict__ Cf, u16* __restrict__ Cb) {
    __shared__ __align__(16) u16 As[128 * 32];
    __shared__ __align__(16) u16 Bs[128 * 32];
    const int tid  = threadIdx.x;
    const int lane = tid & 63;
    const int wv   = tid >> 6;
    const int wr   = (wv >> 1) * 64;       // wave row offset in tile
    const int wc   = (wv & 1) * 64;        // wave col offset in tile
    const int m0   = blockIdx.x * 128;
    const int n0   = blockIdx.y * 128;
    const int fr   = lane & 15;
    const int kg   = (lane >> 4) * 8;      // k-group element offset
    const int srow = tid >> 2;             // staging row 0..63
    const int skc  = (tid & 3) * 8;        // staging k element offset

    f32x4 acc[4][4] = {};
    const size_t a_base = (size_t)(m0 + srow) * DIM + skc;
    const size_t b_base = (size_t)(n0 + srow) * DIM + skc;

    for (int k0 = 0; k0 < DIM; k0 += 32) {
        __builtin_amdgcn_global_load_lds((AS1 void*)(A + a_base + k0),
                                         (AS3 void*)(As + tid * 8), 16, 0, 0);
        __builtin_amdgcn_global_load_lds((AS1 void*)(A + a_base + (size_t)64 * DIM + k0),
                                         (AS3 void*)(As + (tid + 256) * 8), 16, 0, 0);
        __builtin_amdgcn_global_load_lds((AS1 void*)(Bw + b_base + k0),
                                         (AS3 void*)(Bs + tid * 8), 16, 0, 0);
        __builtin_amdgcn_global_load_lds((AS1 void*)(Bw + b_base + (size_t)64 * DIM + k0),
                                         (AS3 void*)(Bs + (tid + 256) * 8), 16, 0, 0);
        __syncthreads();
        bf16x8 af[4], bfr[4];
#pragma unroll
        for (int i = 0; i < 4; ++i)
            af[i] = *(const bf16x8*)(As + (wr + i * 16 + fr) * 32 + kg);
#pragma unroll
        for (int j = 0; j < 4; ++j)
            bfr[j] = *(const bf16x8*)(Bs + (wc + j * 16 + fr) * 32 + kg);
#pragma unroll
        for (int i = 0; i < 4; ++i)
#pragma unroll
            for (int j = 0; j < 4; ++j)
                acc[i][j] = __builtin_amdgcn_mfma_f32_16x16x32_bf16(af[i], bfr[j], acc[i][j], 0, 0, 0);
        __syncthreads();
    }

    const int rb_ = (lane >> 4) * 4;
#pragma unroll
    for (int i = 0; i < 4; ++i) {
#pragma unroll
        for (int j = 0; j < 4; ++j) {
#pragma unroll
            for (int rg = 0; rg < 4; ++rg) {
                const int row = m0 + wr + i * 16 + rb_ + rg;
                const int col = n0 + wc + j * 16 + fr;
                const float val = acc[i][j][rg];
                if (EPI == 0) {
                    Cf[(size_t)row * DIM + col] = val;
                } else if (EPI == 1) {
                    Cb[(size_t)row * DIM + col] = f2bf(1.0f / (1.0f + expf(-val)));
                } else {
                    Cb[(size_t)row * DIM + col] = f2bf(val);
                }
            }
        }
    }
}

// dual-accumulator GEMM: ewk = exp( x@Wk^T - exp(x@Ww^T) ), bf16 out
__global__ void __launch_bounds__(256, 2)
gemm_ewk(const u16* __restrict__ A, const u16* __restrict__ Wk,
         const u16* __restrict__ Ww, u16* __restrict__ E) {
    __shared__ __align__(16) u16 As[128 * 32];
    __shared__ __align__(16) u16 Ks[128 * 32];
    __shared__ __align__(16) u16 Ws[128 * 32];
    const int tid  = threadIdx.x;
    const int lane = tid & 63;
    const int wv   = tid >> 6;
    const int wr   = (wv >> 1) * 64;
    const int wc   = (wv & 1) * 64;
    const int m0   = blockIdx.x * 128;
    const int n0   = blockIdx.y * 128;
    const int fr   = lane & 15;
    const int kg   = (lane >> 4) * 8;
    const int srow = tid >> 2;
    const int skc  = (tid & 3) * 8;

    f32x4 acck[4][4] = {};
    f32x4 accw[4][4] = {};
    const size_t a_base = (size_t)(m0 + srow) * DIM + skc;
    const size_t b_base = (size_t)(n0 + srow) * DIM + skc;

    for (int k0 = 0; k0 < DIM; k0 += 32) {
        __builtin_amdgcn_global_load_lds((AS1 void*)(A + a_base + k0),
                                         (AS3 void*)(As + tid * 8), 16, 0, 0);
        __builtin_amdgcn_global_load_lds((AS1 void*)(A + a_base + (size_t)64 * DIM + k0),
                                         (AS3 void*)(As + (tid + 256) * 8), 16, 0, 0);
        __builtin_amdgcn_global_load_lds((AS1 void*)(Wk + b_base + k0),
                                         (AS3 void*)(Ks + tid * 8), 16, 0, 0);
        __builtin_amdgcn_global_load_lds((AS1 void*)(Wk + b_base + (size_t)64 * DIM + k0),
                                         (AS3 void*)(Ks + (tid + 256) * 8), 16, 0, 0);
        __builtin_amdgcn_global_load_lds((AS1 void*)(Ww + b_base + k0),
                                         (AS3 void*)(Ws + tid * 8), 16, 0, 0);
        __builtin_amdgcn_global_load_lds((AS1 void*)(Ww + b_base + (size_t)64 * DIM + k0),
                                         (AS3 void*)(Ws + (tid + 256) * 8), 16, 0, 0);
        __syncthreads();
        bf16x8 af[4], kf[4], wf[4];
#pragma unroll
        for (int i = 0; i < 4; ++i)
            af[i] = *(const bf16x8*)(As + (wr + i * 16 + fr) * 32 + kg);
#pragma unroll
        for (int j = 0; j < 4; ++j) {
            kf[j] = *(const bf16x8*)(Ks + (wc + j * 16 + fr) * 32 + kg);
            wf[j] = *(const bf16x8*)(Ws + (wc + j * 16 + fr) * 32 + kg);
        }
#pragma unroll
        for (int i = 0; i < 4; ++i)
#pragma unroll
            for (int j = 0; j < 4; ++j) {
                acck[i][j] = __builtin_amdgcn_mfma_f32_16x16x32_bf16(af[i], kf[j], acck[i][j], 0, 0, 0);
                accw[i][j] = __builtin_amdgcn_mfma_f32_16x16x32_bf16(af[i], wf[j], accw[i][j], 0, 0, 0);
            }
        __syncthreads();
    }

    const int rb_ = (lane >> 4) * 4;
#pragma unroll
    for (int i = 0; i < 4; ++i)
#pragma unroll
        for (int j = 0; j < 4; ++j)
#pragma unroll
            for (int rg = 0; rg < 4; ++rg) {
                const int row = m0 + wr + i * 16 + rb_ + rg;
                const int col = n0 + wc + j * 16 + fr;
                const float e = expf(acck[i][j][rg] - expf(accw[i][j][rg]));
                E[(size_t)row * DIM + col] = f2bf(e);
            }
}

// pass 1: per-chunk carries with zero init. grid = BATCH*NCHUNK blocks, 256 thr, 8 ch/thread
__global__ void __launch_bounds__(256)
scan_carry(const u16* __restrict__ ewk, const u16* __restrict__ v,
           const float* __restrict__ td,
           float* __restrict__ carN, float* __restrict__ carD) {
    const int b  = blockIdx.x / NCHUNK;
    const int c  = blockIdx.x % NCHUNK;
    const int d0 = threadIdx.x * 8;
    float dec[8], num[8], den[8];
#pragma unroll
    for (int z = 0; z < 8; ++z) { dec[z] = expf(td[d0 + z]); num[z] = 0.f; den[z] = 0.f; }
    const size_t base = ((size_t)b * SEQ + (size_t)c * CLEN) * DIM + d0;
    for (int t = 0; t < CLEN; ++t) {
        uint4 eu = *(const uint4*)(ewk + base + (size_t)t * DIM);
        uint4 vu = *(const uint4*)(v   + base + (size_t)t * DIM);
        float e[8], vv[8];
        unpack8(eu, e); unpack8(vu, vv);
#pragma unroll
        for (int z = 0; z < 8; ++z) {
            num[z] = dec[z] * num[z] + e[z] * vv[z];
            den[z] = dec[z] * den[z] + e[z];
        }
    }
    const size_t cb = ((size_t)(b * NCHUNK + c)) * DIM + d0;
    *(float4*)(carN + cb)     = { num[0], num[1], num[2], num[3] };
    *(float4*)(carN + cb + 4) = { num[4], num[5], num[6], num[7] };
    *(float4*)(carD + cb)     = { den[0], den[1], den[2], den[3] };
    *(float4*)(carD + cb + 4) = { den[4], den[5], den[6], den[7] };
}

// pass 2: sequential compose over chunks; writes chunk-start states + final_state
__global__ void __launch_bounds__(256)
scan_combine(const float* __restrict__ carN, const float* __restrict__ carD,
             const float* __restrict__ td,
             float* __restrict__ stN, float* __restrict__ stD,
             float* __restrict__ fs) {
    const int i = blockIdx.x * 256 + threadIdx.x;   // 0 .. BATCH*DIM-1
    const int b = i >> 11;
    const int d = i & (DIM - 1);
    const float decL = expf(td[d] * (float)CLEN);
    float num = 0.f, den = 0.f;
    for (int c = 0; c < NCHUNK; ++c) {
        const size_t idx = ((size_t)(b * NCHUNK + c)) * DIM + d;
        stN[idx] = num; stD[idx] = den;
        num = decL * num + carN[idx];
        den = decL * den + carD[idx];
    }
    fs[(size_t)b * 2 * DIM + d]       = num;
    fs[(size_t)b * 2 * DIM + DIM + d] = den;
}

// pass 3: re-scan from true start state, emit y = r * num/(den+1e-8) as bf16
__global__ void __launch_bounds__(256)
scan_apply(const u16* __restrict__ ewk, const u16* __restrict__ v,
           const u16* __restrict__ r, const float* __restrict__ td,
           const float* __restrict__ stN, const float* __restrict__ stD,
           u16* __restrict__ y) {
    const int b  = blockIdx.x / NCHUNK;
    const int c  = blockIdx.x % NCHUNK;
    const int d0 = threadIdx.x * 8;
    float dec[8], num[8], den[8];
    const size_t sb = ((size_t)(b * NCHUNK + c)) * DIM + d0;
    {
        float4 n0_ = *(const float4*)(stN + sb), n1_ = *(const float4*)(stN + sb + 4);
        float4 e0_ = *(const float4*)(stD + sb), e1_ = *(const float4*)(stD + sb + 4);
        num[0]=n0_.x; num[1]=n0_.y; num[2]=n0_.z; num[3]=n0_.w;
        num[4]=n1_.x; num[5]=n1_.y; num[6]=n1_.z; num[7]=n1_.w;
        den[0]=e0_.x; den[1]=e0_.y; den[2]=e0_.z; den[3]=e0_.w;
        den[4]=e1_.x; den[5]=e1_.y; den[6]=e1_.z; den[7]=e1_.w;
    }
#pragma unroll
    for (int z = 0; z < 8; ++z) dec[z] = expf(td[d0 + z]);
    const size_t base = ((size_t)b * SEQ + (size_t)c * CLEN) * DIM + d0;
    for (int t = 0; t < CLEN; ++t) {
        uint4 eu = *(const uint4*)(ewk + base + (size_t)t * DIM);
        uint4 vu = *(const uint4*)(v   + base + (size_t)t * DIM);
        uint4 ru = *(const uint4*)(r   + base + (size_t)t * DIM);
        float e[8], vv[8], rr[8], yy[8];
        unpack8(eu, e); unpack8(vu, vv); unpack8(ru, rr);
#pragma unroll
        for (int z = 0; z < 8; ++z) {
            num[z] = dec[z] * num[z] + e[z] * vv[z];
            den[z] = dec[z] * den[z] + e[z];
            yy[z]  = rr[z] * (num[z] / (den[z] + 1e-8f));
        }
        uint4 o = { pack2(yy[0], yy[1]), pack2(yy[2], yy[3]),
                    pack2(yy[4], yy[5]), pack2(yy[6], yy[7]) };
        *(uint4*)(y + base + (size_t)t * DIM) = o;
    }
}

extern "C" void kernel_launch(void* const* d_in, const int* in_sizes, int n_in,
                              void* d_out, int out_size, void* d_ws, size_t ws_size,
                              hipStream_t stream) {
    const float* x  = (const float*)d_in[0];
    const float* Wr = (const float*)d_in[1];
    const float* Ww = (const float*)d_in[2];
    const float* Wk = (const float*)d_in[3];
    const float* Wv = (const float*)d_in[4];
    const float* Wo = (const float*)d_in[5];
    const float* td = (const float*)d_in[6];
    float* out = (float*)d_out;
    float* fs  = out + (size_t)MROWS * DIM;   // final_state [B,2,D]

    // workspace carve-up (~376 MiB)
    uint8_t* w = (uint8_t*)d_ws;
    auto take = [&](size_t bytes) { void* p = (void*)w; w += bytes; return p; };
    u16* xb   = (u16*)take((size_t)MROWS * DIM * 2);
    u16* Wrb  = (u16*)take((size_t)DIM * DIM * 2);
    u16* Wwb  = (u16*)take((size_t)DIM * DIM * 2);
    u16* Wkb  = (u16*)take((size_t)DIM * DIM * 2);
    u16* Wvb  = (u16*)take((size_t)DIM * DIM * 2);
    u16* Wob  = (u16*)take((size_t)DIM * DIM * 2);
    u16* rb   = (u16*)take((size_t)MROWS * DIM * 2);
    u16* vb   = (u16*)take((size_t)MROWS * DIM * 2);
    u16* ewkb = (u16*)take((size_t)MROWS * DIM * 2);
    u16* yb   = (u16*)take((size_t)MROWS * DIM * 2);
    float* carN = (float*)take((size_t)BATCH * NCHUNK * DIM * 4);
    float* carD = (float*)take((size_t)BATCH * NCHUNK * DIM * 4);
    float* stN  = (float*)take((size_t)BATCH * NCHUNK * DIM * 4);
    float* stD  = (float*)take((size_t)BATCH * NCHUNK * DIM * 4);

    // bf16 conversions
    cvt_kernel<<<(MROWS * DIM) / 1024, 256, 0, stream>>>(x, xb);
    cvt_kernel<<<(DIM * DIM) / 1024, 256, 0, stream>>>(Wr, Wrb);
    cvt_kernel<<<(DIM * DIM) / 1024, 256, 0, stream>>>(Ww, Wwb);
    cvt_kernel<<<(DIM * DIM) / 1024, 256, 0, stream>>>(Wk, Wkb);
    cvt_kernel<<<(DIM * DIM) / 1024, 256, 0, stream>>>(Wv, Wvb);
    cvt_kernel<<<(DIM * DIM) / 1024, 256, 0, stream>>>(Wo, Wob);

    dim3 gg(MROWS / 128, DIM / 128);
    gemm_nt<1><<<gg, 256, 0, stream>>>(xb, Wrb, nullptr, rb);   // r = sigmoid
    gemm_nt<2><<<gg, 256, 0, stream>>>(xb, Wvb, nullptr, vb);   // v
    gemm_ewk  <<<gg, 256, 0, stream>>>(xb, Wkb, Wwb, ewkb);     // ewk

    scan_carry  <<<BATCH * NCHUNK, 256, 0, stream>>>(ewkb, vb, td, carN, carD);
    scan_combine<<<(BATCH * DIM) / 256, 256, 0, stream>>>(carN, carD, td, stN, stD, fs);
    scan_apply  <<<BATCH * NCHUNK, 256, 0, stream>>>(ewkb, vb, rb, td, stN, stD, yb);

    gemm_nt<0><<<gg, 256, 0, stream>>>(yb, Wob, out, nullptr);  // out fp32
}